// Round 6
// baseline (16689.339 us; speedup 1.0000x reference)
//
#include <hip/hip_runtime.h>
#include <hip/hip_bf16.h>

// ---------------------------------------------------------------------------
// BasicDGCNN forward, MI355X (gfx950). Inputs f32, output f32.
// Output layout (f32, flat): [0,768) vertex | [768,772) num_vertices |
// [772,776) nvs | [776,1800) gfeat | [1800,..) x_concat [4,8192,224].
//
// Round-17 (resubmit; prior run died to container infra, no data): phase A
// no longer maintains EXACT per-split top-21 (insert1 + drains + xjf staging
// deleted). Insight: phase B only needs a J-ASCENDING SUPERSET of each
// split's exact top-21 (it recomputes exactly and inserts with strict <
// => jax-stable). Phase A = two passes over the split:
//   pass1: approx f16-MFMA distances -> register chain a[21] (values only);
//   pass2: re-stage+MFMA, emit j's with d_approx < a21 + 2*margin into a
//          31-slot per-split list (j-ascending); overflow -> 0xFFFF flag.
// Phase B: per split, insert candidates (or full exact rescan if flagged)
// with the byte-identical r12 chain -> final idx bit-identical. Margins:
// C1=0.0015 (f16 dot+store, near-rigorous) C2=2^-16 (f32 chain), applied
// on both the a21-gap and catch sides. LDS 29.3KB (5 blk/CU), dist f16
// with sxj folded at MFMA write. absmax must stay 0.2949219 exactly.
// ---------------------------------------------------------------------------

#define NPTS 8192
#define BATCH 4
#define KNBR 20

typedef _Float16 half8 __attribute__((ext_vector_type(8)));
typedef _Float16 half4 __attribute__((ext_vector_type(4)));
typedef float f32x4 __attribute__((ext_vector_type(4)));

__device__ __forceinline__ int cswz(int r, int nc) {   // f16-chunk swizzle
    return (nc == 8) ? (r & 7) : ((r >> 1) & 3);
}

// ===================== KNN phase A: approx superset per split ==============
// grid (ROWS/128, S); block 128 thr (2 waves). Block owns 128 queries.
template <int D, int DK, int RS, int S>
__global__ __launch_bounds__(128, 2) void knn_part_mfma(
    const float* feat, float* xcat) {
    constexpr int TJ  = 32;
    constexpr int CAP = 31;                  // emit slots per split
    constexpr int BSTR= 33;                  // bufe row stride (u16)
    constexpr int JC  = NPTS / S;            // 1024
    constexpr int NT  = JC / TJ;             // 32 tiles
    constexpr int NC  = DK / 8;
    constexpr int KS  = DK / 32;
    constexpr int OFF_XJH = 16384;
    constexpr int OFF_BUFE= OFF_XJH + TJ * DK * 2;
    constexpr int OFF_MEA = OFF_BUFE + 128 * BSTR * 2;
    constexpr int OFF_TMX = OFF_MEA + ((D * 4 + 15) & ~15);
    __shared__ __align__(16) char smem[OFF_TMX + NT * 4];

    _Float16*       xih  = (_Float16*)smem;              // setup only (<=16K)
    _Float16*       dist = (_Float16*)smem;              // [128][32] f16 swz
    float*          mtmp = (float*)smem;                 // [1024] setup only
    float*          sxj  = (float*)(smem + 8192);        // [1024] centered
    _Float16*       xjh  = (_Float16*)(smem + OFF_XJH);  // centered f16 tile
    unsigned short* bufe = (unsigned short*)(smem + OFF_BUFE);
    float*          meanp= (float*)(smem + OFF_MEA);
    float*          tmax = (float*)(smem + OFF_TMX);     // per-tile j-margin

    const int tid   = threadIdx.x;
    const int gi    = blockIdx.x * 128 + tid;
    const int s     = blockIdx.y;
    const int b     = gi >> 13;
    const int ib    = gi & (NPTS - 1);
    const int n0b   = (blockIdx.x * 128) & (NPTS - 1);
    const int sbase = s * JC;
    const float* fb = feat + (size_t)b * NPTS * RS;

    const float C1 = 0.0015f;               // f16 dot+store bound (~rigor)
    const float C2 = 1.52587890625e-05f;    // 2^-16 f32 exact-chain cover

    // ---- center = block's first query row ----
    if (tid < D) meanp[tid] = fb[(size_t)n0b * RS + tid];
    __syncthreads();

    // ---- own row: s_i (centered norm), xxi (margin only, not exactness) --
    float s_i = 0.f, xxi = 0.f;
    {
        const float* row = fb + (size_t)ib * RS;
        if (D % 4 == 0) {
            #pragma unroll
            for (int c4 = 0; c4 < D / 4; ++c4) {
                float4 v = *(const float4*)(row + 4 * c4);
                float4 m = *(const float4*)(meanp + 4 * c4);
                xxi = fmaf(v.x, v.x, xxi); xxi = fmaf(v.y, v.y, xxi);
                xxi = fmaf(v.z, v.z, xxi); xxi = fmaf(v.w, v.w, xxi);
                float d0 = v.x - m.x, d1 = v.y - m.y;
                float d2 = v.z - m.z, d3 = v.w - m.w;
                s_i = fmaf(d0, d0, s_i); s_i = fmaf(d1, d1, s_i);
                s_i = fmaf(d2, d2, s_i); s_i = fmaf(d3, d3, s_i);
            }
        } else {
            #pragma unroll
            for (int c = 0; c < D; ++c) {
                float v = row[c];
                xxi = fmaf(v, v, xxi);
                float d = v - meanp[c];
                s_i = fmaf(d, d, s_i);
            }
        }
    }

    // ---- stage xih: 128 query rows, CENTERED f16, swizzled ----
    for (int e = tid; e < 128 * NC; e += 128) {
        int r = e / NC, c = e % NC;
        const float* row = fb + (size_t)(n0b + r) * RS;
        half8 h;
        if (D % 8 == 0) {
            float4 v0 = *(const float4*)(row + c * 8);
            float4 v1 = *(const float4*)(row + c * 8 + 4);
            float4 m0 = *(const float4*)(meanp + c * 8);
            float4 m1 = *(const float4*)(meanp + c * 8 + 4);
            h[0] = (_Float16)(v0.x - m0.x); h[1] = (_Float16)(v0.y - m0.y);
            h[2] = (_Float16)(v0.z - m0.z); h[3] = (_Float16)(v0.w - m0.w);
            h[4] = (_Float16)(v1.x - m1.x); h[5] = (_Float16)(v1.y - m1.y);
            h[6] = (_Float16)(v1.z - m1.z); h[7] = (_Float16)(v1.w - m1.w);
        } else {
            #pragma unroll
            for (int t = 0; t < 8; ++t) {
                int dim = c * 8 + t;
                h[t] = (dim < D) ? (_Float16)(row[dim] - meanp[dim])
                                 : (_Float16)0.f;
            }
        }
        *(half8*)(xih + (size_t)r * DK + (c ^ cswz(r, NC)) * 8) = h;
    }
    __syncthreads();

    // ---- B-fragments (this wave's 64 queries) ----
    const int lane = tid & 63, wid = tid >> 6;
    const int ln = lane & 15, lg = lane >> 4;
    half8 bfr[4][KS];
    #pragma unroll
    for (int qs = 0; qs < 4; ++qs)
        #pragma unroll
        for (int ks = 0; ks < KS; ++ks) {
            int q = wid * 64 + qs * 16 + ln;
            bfr[qs][ks] = *(const half8*)(
                xih + (size_t)q * DK + (((lg + 4 * ks) ^ cswz(q, NC)) * 8));
        }
    __syncthreads();                         // xih dead; region -> mtmp/sxj

    // ---- sxj (centered norms) + per-j margin scalars ----
    for (int r = tid; r < JC; r += 128) {
        const float* row = fb + (size_t)(sbase + r) * RS;
        float sc = 0.f, xx = 0.f;
        if (D % 4 == 0) {
            #pragma unroll
            for (int c4 = 0; c4 < D / 4; ++c4) {
                float4 v = *(const float4*)(row + 4 * c4);
                float4 m = *(const float4*)(meanp + 4 * c4);
                xx = fmaf(v.x, v.x, xx); xx = fmaf(v.y, v.y, xx);
                xx = fmaf(v.z, v.z, xx); xx = fmaf(v.w, v.w, xx);
                float d0 = v.x - m.x, d1 = v.y - m.y;
                float d2 = v.z - m.z, d3 = v.w - m.w;
                sc = fmaf(d0, d0, sc); sc = fmaf(d1, d1, sc);
                sc = fmaf(d2, d2, sc); sc = fmaf(d3, d3, sc);
            }
        } else {
            #pragma unroll
            for (int c = 0; c < D; ++c) {
                float v = row[c];
                xx = fmaf(v, v, xx);
                float d = v - meanp[c];
                sc = fmaf(d, d, sc);
            }
        }
        sxj[r] = sc;
        mtmp[r] = fmaf(C1, sc, C2 * xx);
    }
    __syncthreads();
    if (tid < NT) {                          // per-tile margin max (rotated)
        float mx = 0.f;
        for (int r = 0; r < TJ; ++r) {
            int j = tid * TJ + ((r + tid) & (TJ - 1));
            mx = fmaxf(mx, mtmp[j]);
        }
        tmax[tid] = mx;
    }
    __syncthreads();
    float tmaxG = 0.f;
    #pragma unroll 1
    for (int t = 0; t < NT; ++t) tmaxG = fmaxf(tmaxG, tmax[t]);
    const float c_i = 2.f * fmaf(C1, s_i, C2 * xxi) + tmaxG;

    // ---- stage + MFMA for one tile (shared by both passes) ----
    auto tile_sm = [&](int t0) {
        if (D % 8 == 0) {
            for (int e = tid; e < TJ * NC; e += 128) {
                int r = e / NC, c = e % NC;
                const float* row = fb + (size_t)(sbase + t0 + r) * RS + c * 8;
                float4 v0 = *(const float4*)(row);
                float4 v1 = *(const float4*)(row + 4);
                float4 m0 = *(const float4*)(meanp + c * 8);
                float4 m1 = *(const float4*)(meanp + c * 8 + 4);
                half8 h;
                h[0] = (_Float16)(v0.x - m0.x); h[1] = (_Float16)(v0.y - m0.y);
                h[2] = (_Float16)(v0.z - m0.z); h[3] = (_Float16)(v0.w - m0.w);
                h[4] = (_Float16)(v1.x - m1.x); h[5] = (_Float16)(v1.y - m1.y);
                h[6] = (_Float16)(v1.z - m1.z); h[7] = (_Float16)(v1.w - m1.w);
                *(half8*)(xjh + (size_t)r * DK + ((c ^ cswz(r, NC)) * 8)) = h;
            }
        } else {
            for (int e = tid; e < TJ * NC; e += 128) {
                int r = e / NC, c = e % NC;
                const float* row = fb + (size_t)(sbase + t0 + r) * RS;
                half8 h;
                #pragma unroll
                for (int q2 = 0; q2 < 8; ++q2) {
                    int dim = c * 8 + q2;
                    h[q2] = (dim < D) ? (_Float16)(row[dim] - meanp[dim])
                                      : (_Float16)0.f;
                }
                *(half8*)(xjh + (size_t)r * DK + ((c ^ cswz(r, NC)) * 8)) = h;
            }
        }
        __syncthreads();
        #pragma unroll
        for (int js = 0; js < TJ / 16; ++js) {
            half8 afr[KS];
            #pragma unroll
            for (int ks = 0; ks < KS; ++ks) {
                int jr = js * 16 + ln;
                afr[ks] = *(const half8*)(
                    xjh + (size_t)jr * DK +
                    (((lg + 4 * ks) ^ cswz(jr, NC)) * 8));
            }
            float4 sx4 = *(const float4*)(sxj + t0 + js * 16 + lg * 4);
            #pragma unroll
            for (int qs = 0; qs < 4; ++qs) {
                f32x4 acc = {0.f, 0.f, 0.f, 0.f};
                #pragma unroll
                for (int ks = 0; ks < KS; ++ks)
                    acc = __builtin_amdgcn_mfma_f32_16x16x32_f16(
                        afr[ks], bfr[qs][ks], acc, 0, 0, 0);
                int q  = wid * 64 + qs * 16 + ln;
                int ck = js * 4 + lg;
                half4 hv;   // sv = sxj - 2*dot~, rows j consecutive per lane
                hv[0] = (_Float16)fmaf(-2.f, acc[0], sx4.x);
                hv[1] = (_Float16)fmaf(-2.f, acc[1], sx4.y);
                hv[2] = (_Float16)fmaf(-2.f, acc[2], sx4.z);
                hv[3] = (_Float16)fmaf(-2.f, acc[3], sx4.w);
                *(half4*)(dist + (size_t)q * 32 + ((ck ^ ((q >> 1) & 7)) * 4)) = hv;
            }
        }
        __syncthreads();
    };

    float a[21];
    #pragma unroll
    for (int t = 0; t < 21; ++t) a[t] = __builtin_inff();
    auto chain = [&](float v) {
        if (v < a[20]) {
            a[20] = v;
            #pragma unroll
            for (int t = 20; t > 0; --t)
                if (a[t] < a[t - 1]) { float tv = a[t]; a[t] = a[t - 1]; a[t - 1] = tv; }
        }
    };

    const int dsw = (tid >> 1) & 7;
    _Float16* drow = dist + (size_t)tid * 32;

    // ======== pass 1: approx top-21 values only ========
    #pragma unroll 1
    for (int t0 = 0; t0 < JC; t0 += TJ) {
        tile_sm(t0);
        #pragma unroll 1
        for (int c = 0; c < TJ / 4; ++c) {
            half4 hv = *(const half4*)(drow + ((c ^ dsw) * 4));
            float f0 = (float)hv[0], f1 = (float)hv[1];
            float f2 = (float)hv[2], f3 = (float)hv[3];
            chain(f0); chain(f1); chain(f2); chain(f3);
        }
    }

    // ======== pass 2: emit superset (j-ascending) ========
    int cnt = 0;
    #pragma unroll 1
    for (int t0 = 0; t0 < JC; t0 += TJ) {
        tile_sm(t0);
        float thr2 = a[20] + c_i + tmax[t0 >> 5];
        #pragma unroll 1
        for (int c = 0; c < TJ / 4; ++c) {
            half4 hv = *(const half4*)(drow + ((c ^ dsw) * 4));
            int jb = t0 + c * 4;
            float f0 = (float)hv[0], f1 = (float)hv[1];
            float f2 = (float)hv[2], f3 = (float)hv[3];
            if (f0 < thr2) { if (cnt < CAP) bufe[tid * BSTR + cnt] = (unsigned short)(jb);     ++cnt; }
            if (f1 < thr2) { if (cnt < CAP) bufe[tid * BSTR + cnt] = (unsigned short)(jb + 1); ++cnt; }
            if (f2 < thr2) { if (cnt < CAP) bufe[tid * BSTR + cnt] = (unsigned short)(jb + 2); ++cnt; }
            if (f3 < thr2) { if (cnt < CAP) bufe[tid * BSTR + cnt] = (unsigned short)(jb + 3); ++cnt; }
        }
    }

    // ---- flush: [cnt | j0..j_{cnt-1}] per split (0xFFFF = overflow flag) --
    unsigned short* sc16 =
        (unsigned short*)(xcat + (size_t)gi * 224 + 96) + s * 32;
    if (cnt > CAP) {
        sc16[0] = 0xFFFFu;                   // phase B rescans this split
    } else {
        sc16[0] = (unsigned short)cnt;
        for (int k = 0; k < cnt; ++k) sc16[1 + k] = bufe[tid * BSTR + k];
    }
}

// ===================== KNN phase B: exact merge ============================
// Candidates per split in j-ascending order; exact r12 fma chains; strict-<
// insertion == jax top_k stability. Flagged split -> full exact rescan.
template <int D, int RS, int S>
__global__ __launch_bounds__(128) void knn_merge(
    const float* feat, const float* xcat, unsigned short* __restrict__ idxout) {
    constexpr int JC = NPTS / S;
    int gi = blockIdx.x * 128 + threadIdx.x;
    int b  = gi >> 13;
    int ib = gi & (NPTS - 1);
    const float* fb = feat + (size_t)b * NPTS * RS;

    float xi[D];
    if (D % 4 == 0) {
        #pragma unroll
        for (int c4 = 0; c4 < D / 4; ++c4) {
            float4 v = *(const float4*)(fb + (size_t)ib * RS + 4 * c4);
            xi[4 * c4] = v.x; xi[4 * c4 + 1] = v.y;
            xi[4 * c4 + 2] = v.z; xi[4 * c4 + 3] = v.w;
        }
    } else {
        #pragma unroll
        for (int c = 0; c < D; ++c) xi[c] = fb[(size_t)ib * RS + c];
    }
    float xxi = 0.f;
    #pragma unroll
    for (int c = 0; c < D; ++c) xxi = fmaf(xi[c], xi[c], xxi);

    const unsigned short* cp =
        (const unsigned short*)(xcat + (size_t)gi * 224 + 96);

    float dl[21];
    int   il[21];
    #pragma unroll
    for (int t = 0; t < 21; ++t) { dl[t] = __builtin_inff(); il[t] = 0; }

    auto ins = [&](int j) {                  // byte-identical r12 chain
        const float* row = fb + (size_t)j * RS;
        float dot = 0.f, xx = 0.f;
        if (D % 4 == 0) {
            #pragma unroll
            for (int c4 = 0; c4 < D / 4; ++c4) {
                float4 v = *(const float4*)(row + 4 * c4);
                dot = fmaf(xi[4 * c4], v.x, dot);     xx = fmaf(v.x, v.x, xx);
                dot = fmaf(xi[4 * c4 + 1], v.y, dot); xx = fmaf(v.y, v.y, xx);
                dot = fmaf(xi[4 * c4 + 2], v.z, dot); xx = fmaf(v.z, v.z, xx);
                dot = fmaf(xi[4 * c4 + 3], v.w, dot); xx = fmaf(v.w, v.w, xx);
            }
        } else {
            #pragma unroll
            for (int c = 0; c < D; ++c) {
                float v = row[c];
                dot = fmaf(xi[c], v, dot);
                xx  = fmaf(v, v, xx);
            }
        }
        float d = __builtin_fmaf(-2.f, dot, xxi + xx);
        if (d < dl[20]) {
            dl[20] = d; il[20] = j;
            #pragma unroll
            for (int u = 20; u > 0; --u) {
                if (dl[u] < dl[u - 1]) {
                    float td = dl[u]; dl[u] = dl[u - 1]; dl[u - 1] = td;
                    int   ti = il[u]; il[u] = il[u - 1]; il[u - 1] = ti;
                }
            }
        }
    };

    #pragma unroll 1
    for (int s = 0; s < S; ++s) {
        int cn = (int)cp[s * 32];
        if (cn == 0xFFFF) {                  // overflow: exact rescan
            #pragma unroll 1
            for (int j = s * JC; j < (s + 1) * JC; ++j) ins(j);
        } else {
            #pragma unroll 1
            for (int k = 0; k < cn; ++k)
                ins(s * JC + ((int)cp[s * 32 + 1 + k] & (JC - 1)));
        }
    }
    unsigned short* op = idxout + (size_t)gi * KNBR;
    #pragma unroll
    for (int t = 1; t < 21; ++t) op[t - 1] = (unsigned short)il[t];
}

// ===================== EdgeConv (fused BN + leaky + max_k) =================
template <int CIN, int RS, int COUT, int OTILE, int P>
__global__ __launch_bounds__(256) void edgeconv_kernel(
    const float* feat, const unsigned short* __restrict__ knn,
    const float* __restrict__ W, const float* __restrict__ g,
    const float* __restrict__ beta, const float* __restrict__ mu,
    const float* __restrict__ var,
    float* outb, int concat_off) {
    __shared__ float diff[P][KNBR][CIN];
    __shared__ float xil[P][CIN];
    __shared__ unsigned short kidx[P * KNBR];
    __shared__ float sl[OTILE], bl[OTILE], ml[OTILE];

    int tid = threadIdx.x;
    int h   = blockIdx.y;
    int n0  = blockIdx.x * P;                 // P divides 8192 -> same batch
    int b   = n0 >> 13;
    const float* fbase = feat + ((size_t)b << 13) * RS;

    for (int e = tid; e < P * CIN; e += 256)
        xil[e / CIN][e % CIN] = feat[(size_t)(n0 + e / CIN) * RS + e % CIN];
    for (int e = tid; e < P * KNBR; e += 256)
        kidx[e] = knn[(size_t)(n0 + e / KNBR) * KNBR + e % KNBR] & (NPTS - 1);
    for (int e = tid; e < OTILE; e += 256) {
        int o = h * OTILE + e;
        sl[e] = g[o] * rsqrtf(var[o] + 1e-5f);
        bl[e] = beta[o];
        ml[e] = mu[o];
    }
    __syncthreads();

    if (CIN % 4 == 0) {
        for (int e = tid; e < P * KNBR * (CIN / 4); e += 256) {
            int r = e / (CIN / 4), c4 = e % (CIN / 4);
            int p = r / KNBR, k = r % KNBR;
            int j = (int)kidx[r];
            float4 v = *(const float4*)(fbase + (size_t)j * RS + 4 * c4);
            diff[p][k][4 * c4 + 0] = v.x - xil[p][4 * c4 + 0];
            diff[p][k][4 * c4 + 1] = v.y - xil[p][4 * c4 + 1];
            diff[p][k][4 * c4 + 2] = v.z - xil[p][4 * c4 + 2];
            diff[p][k][4 * c4 + 3] = v.w - xil[p][4 * c4 + 3];
        }
    } else {
        for (int e = tid; e < P * KNBR * CIN; e += 256) {
            int r = e / CIN, c = e % CIN;
            int pp = r / KNBR, k = r % KNBR;
            int j = (int)kidx[r];
            diff[pp][k][c] = fbase[(size_t)j * RS + c] - xil[pp][c];
        }
    }
    __syncthreads();

    int ol = tid % OTILE, p = tid / OTILE;
    int o  = h * OTILE + ol;

    float wreg[CIN];
    #pragma unroll
    for (int c = 0; c < CIN; ++c) wreg[c] = W[(size_t)o * (2 * CIN) + c];
    float a = 0.f;
    #pragma unroll
    for (int c = 0; c < CIN; ++c) a = fmaf(wreg[c], xil[p][c], a);
    #pragma unroll
    for (int c = 0; c < CIN; ++c) wreg[c] = W[(size_t)o * (2 * CIN) + CIN + c];

    float s = sl[ol], mm = ml[ol], bb = bl[ol];
    float best = -__builtin_inff();
    for (int k = 0; k < KNBR; ++k) {
        float ac0 = a, ac1 = 0.f, ac2 = 0.f, ac3 = 0.f;
        #pragma unroll
        for (int c = 0; c < CIN; ++c) {
            float d = diff[p][k][c];
            if ((c & 3) == 0)      ac0 = fmaf(wreg[c], d, ac0);
            else if ((c & 3) == 1) ac1 = fmaf(wreg[c], d, ac1);
            else if ((c & 3) == 2) ac2 = fmaf(wreg[c], d, ac2);
            else                   ac3 = fmaf(wreg[c], d, ac3);
        }
        float acc = ((ac0 + ac1) + ac2) + ac3;
        float y = (acc - mm) * s + bb;
        y = (y >= 0.f) ? y : 0.2f * y;
        best = fmaxf(best, y);
    }
    outb[(size_t)(n0 + p) * 224 + concat_off + o] = best;
}

// ===================== conv_global: LDS-tiled GEMM + fused max =============
__global__ __launch_bounds__(256) void convglobal_kernel(
    const float* __restrict__ xcat,
    const float* __restrict__ Wg, const float* __restrict__ gg,
    const float* __restrict__ bg, const float* __restrict__ mg,
    const float* __restrict__ vg,
    float* __restrict__ partial) {
    const int KC = 56, PT = 64, OT = 64, ST = 68;   // ST: padded row stride
    __shared__ float flT[KC * ST];                  // [c][p]  15.2 KB
    __shared__ float WlT[KC * ST];                  // [c][o]  15.2 KB
    __shared__ float red[64 * 17];                  //          4.4 KB

    int tid = threadIdx.x;
    int oi  = tid & 15, pi = tid >> 4;
    int o0  = blockIdx.y * OT;
    int n0  = blockIdx.x * PT;                      // 64 | 8192 -> same batch
    int b   = n0 >> 13;
    int pchunk = blockIdx.x & 127;                  // chunk within batch

    float acc[4][4];
    #pragma unroll
    for (int u = 0; u < 4; ++u)
        #pragma unroll
        for (int v = 0; v < 4; ++v) acc[u][v] = 0.f;

    for (int kc = 0; kc < 224; kc += KC) {
        __syncthreads();
        for (int e = tid; e < PT * (KC / 4); e += 256) {
            int p = e / (KC / 4), c4 = e % (KC / 4);
            float4 v = *(const float4*)(xcat + (size_t)(n0 + p) * 224 + kc + 4 * c4);
            flT[(4 * c4 + 0) * ST + p] = v.x;
            flT[(4 * c4 + 1) * ST + p] = v.y;
            flT[(4 * c4 + 2) * ST + p] = v.z;
            flT[(4 * c4 + 3) * ST + p] = v.w;
        }
        for (int e = tid; e < OT * (KC / 4); e += 256) {
            int o = e / (KC / 4), c4 = e % (KC / 4);
            float4 v = *(const float4*)(Wg + (size_t)(o0 + o) * 224 + kc + 4 * c4);
            WlT[(4 * c4 + 0) * ST + o] = v.x;
            WlT[(4 * c4 + 1) * ST + o] = v.y;
            WlT[(4 * c4 + 2) * ST + o] = v.z;
            WlT[(4 * c4 + 3) * ST + o] = v.w;
        }
        __syncthreads();
        #pragma unroll 8
        for (int c = 0; c < KC; ++c) {
            float4 w4 = *(const float4*)(WlT + c * ST + oi * 4);
            float4 f4 = *(const float4*)(flT + c * ST + pi * 4);
            acc[0][0] = fmaf(w4.x, f4.x, acc[0][0]);
            acc[0][1] = fmaf(w4.x, f4.y, acc[0][1]);
            acc[0][2] = fmaf(w4.x, f4.z, acc[0][2]);
            acc[0][3] = fmaf(w4.x, f4.w, acc[0][3]);
            acc[1][0] = fmaf(w4.y, f4.x, acc[1][0]);
            acc[1][1] = fmaf(w4.y, f4.y, acc[1][1]);
            acc[1][2] = fmaf(w4.y, f4.z, acc[1][2]);
            acc[1][3] = fmaf(w4.y, f4.w, acc[1][3]);
            acc[2][0] = fmaf(w4.z, f4.x, acc[2][0]);
            acc[2][1] = fmaf(w4.z, f4.y, acc[2][1]);
            acc[2][2] = fmaf(w4.z, f4.z, acc[2][2]);
            acc[2][3] = fmaf(w4.z, f4.w, acc[2][3]);
            acc[3][0] = fmaf(w4.w, f4.x, acc[3][0]);
            acc[3][1] = fmaf(w4.w, f4.y, acc[3][1]);
            acc[3][2] = fmaf(w4.w, f4.z, acc[3][2]);
            acc[3][3] = fmaf(w4.w, f4.w, acc[3][3]);
        }
    }
    #pragma unroll
    for (int u = 0; u < 4; ++u) {
        int oL = oi * 4 + u, o = o0 + oL;
        float s = gg[o] * rsqrtf(vg[o] + 1e-5f);
        float mm = mg[o], bb = bg[o];
        float best = -__builtin_inff();
        #pragma unroll
        for (int v = 0; v < 4; ++v) {
            float y = (acc[u][v] - mm) * s + bb;
            y = (y >= 0.f) ? y : 0.2f * y;
            best = fmaxf(best, y);
        }
        red[oL * 17 + pi] = best;
    }
    __syncthreads();
    if (tid < 64) {
        float best = -__builtin_inff();
        #pragma unroll
        for (int q = 0; q < 16; ++q) best = fmaxf(best, red[tid * 17 + q]);
        partial[((size_t)(b * 128 + pchunk)) * 256 + o0 + tid] = best;
    }
}

__global__ void reduce_gfeat_kernel(const float* __restrict__ partial,
                                    float* __restrict__ gfeat,
                                    float* __restrict__ outg) {
    int b = blockIdx.x, o = threadIdx.x;
    float best = -__builtin_inff();
    for (int ch = 0; ch < 128; ++ch)
        best = fmaxf(best, partial[((size_t)b * 128 + ch) * 256 + o]);
    gfeat[b * 256 + o] = best;
    outg[b * 256 + o]  = best;
}

// ===================== heads (per-batch block) =============================
__global__ __launch_bounds__(256) void heads_kernel(
    const float* __restrict__ gfeat,
    const float* __restrict__ Wv1, const float* __restrict__ bv1,
    const float* __restrict__ Wv2, const float* __restrict__ bv2,
    const float* __restrict__ Wq1, const float* __restrict__ bq1,
    const float* __restrict__ Wq2, const float* __restrict__ bq2,
    float* __restrict__ out) {
    int b = blockIdx.x, t = threadIdx.x;
    __shared__ float gf[256], h[512], q[64];
    gf[t] = gfeat[b * 256 + t];
    __syncthreads();
    for (int r = t; r < 512; r += 256) {
        float acc = bv1[r];
        for (int c = 0; c < 256; ++c) acc = fmaf(Wv1[r * 256 + c], gf[c], acc);
        h[r] = fmaxf(acc, 0.f);
    }
    __syncthreads();
    if (t < 192) {
        float acc = bv2[t];
        for (int c = 0; c < 512; ++c) acc = fmaf(Wv2[t * 512 + c], h[c], acc);
        out[b * 192 + t] = acc;               // vertex_coords
    } else {
        int r = t - 192;
        if (r < 64) {
            float acc = bq1[r];
            for (int c = 0; c < 256; ++c) acc = fmaf(Wq1[r * 256 + c], gf[c], acc);
            q[r] = fmaxf(acc, 0.f);
        }
    }
    __syncthreads();
    if (t == 0) {
        float acc = bq2[0];
        for (int c = 0; c < 64; ++c) acc = fmaf(Wq2[c], q[c], acc);
        float nv = 1.0f / (1.0f + expf(-acc));
        out[772 + b] = nv;                                       // nvs
        float num = fminf(fmaxf(rintf(nv * 64.0f), 1.0f), 64.0f);
        out[768 + b] = num;                                      // num_vertices
    }
}

// ============================== launch =====================================
extern "C" void kernel_launch(void* const* d_in, const int* in_sizes, int n_in,
                              void* d_out, int out_size, void* d_ws, size_t ws_size,
                              hipStream_t stream) {
    (void)in_sizes; (void)n_in; (void)out_size; (void)ws_size;
    const float* x   = (const float*)d_in[0];
    const float* W1  = (const float*)d_in[1];
    const float* g1  = (const float*)d_in[2];
    const float* b1  = (const float*)d_in[3];
    const float* m1  = (const float*)d_in[4];
    const float* v1  = (const float*)d_in[5];
    const float* W2  = (const float*)d_in[6];
    const float* g2  = (const float*)d_in[7];
    const float* b2  = (const float*)d_in[8];
    const float* m2  = (const float*)d_in[9];
    const float* v2  = (const float*)d_in[10];
    const float* W3  = (const float*)d_in[11];
    const float* g3  = (const float*)d_in[12];
    const float* b3  = (const float*)d_in[13];
    const float* m3  = (const float*)d_in[14];
    const float* v3  = (const float*)d_in[15];
    const float* Wg  = (const float*)d_in[16];
    const float* gg  = (const float*)d_in[17];
    const float* bg  = (const float*)d_in[18];
    const float* mg  = (const float*)d_in[19];
    const float* vg  = (const float*)d_in[20];
    const float* Wv1 = (const float*)d_in[21];
    const float* bv1 = (const float*)d_in[22];
    const float* Wv2 = (const float*)d_in[23];
    const float* bv2 = (const float*)d_in[24];
    const float* Wq1 = (const float*)d_in[25];
    const float* bq1 = (const float*)d_in[26];
    const float* Wq2 = (const float*)d_in[27];
    const float* bq2 = (const float*)d_in[28];

    float* out  = (float*)d_out;
    float* xcat = out + 1800;                    // f32 [4,8192,224]
    char* ws = (char*)d_ws;
    const int ROWS = BATCH * NPTS;   // 32768

    // ws layout (1,310,720 B; part/gft alias idx AFTER it is dead):
    unsigned short* idx  = (unsigned short*)(ws);        // [32768,20] u16
    float*          part = (float*)(ws);                 // [512,256] f32 (alias)
    float*          gft  = (float*)(ws + 524288);        // [4,256]   f32 (alias)

    // ---- EdgeConv 1: 5 -> 32
    knn_part_mfma<5, 32, 5, 8><<<dim3(ROWS / 128, 8), 128, 0, stream>>>(x, xcat);
    knn_merge<5, 5, 8><<<ROWS / 128, 128, 0, stream>>>(x, xcat, idx);
    edgeconv_kernel<5, 5, 32, 32, 8>
        <<<dim3(ROWS / 8, 1), 256, 0, stream>>>(x, idx, W1, g1, b1, m1, v1, xcat, 0);

    // ---- EdgeConv 2: 32 -> 64 (features from xcat[:,0:32))
    knn_part_mfma<32, 32, 224, 8><<<dim3(ROWS / 128, 8), 128, 0, stream>>>(xcat, xcat);
    knn_merge<32, 224, 8><<<ROWS / 128, 128, 0, stream>>>(xcat, xcat, idx);
    edgeconv_kernel<32, 224, 64, 64, 4>
        <<<dim3(ROWS / 4, 1), 256, 0, stream>>>(xcat, idx, W2, g2, b2, m2, v2, xcat, 32);

    // ---- EdgeConv 3: 64 -> 128 (features from xcat[:,32:96))
    knn_part_mfma<64, 64, 224, 8><<<dim3(ROWS / 128, 8), 128, 0, stream>>>(xcat + 32, xcat);
    knn_merge<64, 224, 8><<<ROWS / 128, 128, 0, stream>>>(xcat + 32, xcat, idx);
    edgeconv_kernel<64, 224, 128, 64, 4>
        <<<dim3(ROWS / 4, 2), 256, 0, stream>>>(xcat + 32, idx, W3, g3, b3, m3, v3, xcat, 96);

    // ---- conv_global (224->256) + max over N  (idx dead; part aliases it)
    convglobal_kernel<<<dim3(ROWS / 64, 4), 256, 0, stream>>>(
        xcat, Wg, gg, bg, mg, vg, part);
    reduce_gfeat_kernel<<<BATCH, 256, 0, stream>>>(part, gft, out + 776);

    // ---- heads
    heads_kernel<<<BATCH, 256, 0, stream>>>(
        gft, Wv1, bv1, Wv2, bv2, Wq1, bq1, Wq2, bq2, out);
}

// Round 7
// 4309.058 us; speedup vs baseline: 3.8731x; 3.8731x over previous
//
#include <hip/hip_runtime.h>
#include <hip/hip_bf16.h>

// ---------------------------------------------------------------------------
// BasicDGCNN forward, MI355X (gfx950). Inputs f32, output f32.
// Output layout (f32, flat): [0,768) vertex | [768,772) num_vertices |
// [772,776) nvs | [776,1800) gfeat | [1800,..) x_concat [4,8192,224].
//
// Round-18: back to the proven r12 structure (3783us). r17's f16-margin
// superset overflowed everywhere (distance concentration: order-stat gaps
// ~0.1-1% of dbar vs f16 margin ~0.3-1%) -> knn_merge rescanned ~all
// splits (8.3ms each). New filter is f32-REASSOCIATION-tight: scan computes
// a 4-accumulator dot (4x ILP on the latency-bound serial chain), tests
// da < thr + 2^-16*(xxi+xxj) (rigorous |da-d| <= 2*gamma_64*sum ~ 7.6e-6*
// sum, 2x slack -> ~zero false passes). Survivors buffer j only; drain
// (on-full + at tile end, xj live) recomputes the BYTE-IDENTICAL ascending
// chain from LDS (XOR-swizzled float4 chunks vs 32-way conflicts) and runs
// r12's strict-< insertion. Bit-exactness: insertable j's always pass the
// pre-test (d<thr => da<thr+eps); extra passers fail dd<dl[20] at drain;
// FIFO j-ascending preserved => top-21 bit-identical => absmax 0.2949219.
// D=5 path and all downstream kernels are r12 verbatim.
// ---------------------------------------------------------------------------

#define NPTS 8192
#define BATCH 4
#define KNBR 20

// ===================== KNN phase A: per-split top-21 =======================
// grid (ROWS/128, S); block 128 thr. thread = query point; j-range
// [s*JC,(s+1)*JC) staged in TJ-row LDS tiles (XOR-swizzled float4 chunks
// when D%4==0). Scan: 4-acc approx dot + EPS pre-test -> buffer j; drain
// recomputes exact ascending chain (== r12/knn_merge) and inserts.
template <int D, int RS, int S, int TJ, int B>
__global__ __launch_bounds__(128, 2) void knn_part(
    const float* feat, float* xcat) {
    constexpr bool PRE = (D % 4 == 0);
    __shared__ float xj[TJ * D];
    __shared__ float xxj[TJ];
    __shared__ float bufd[PRE ? 1 : B * 128];     // r12 path only (D=5)
    __shared__ unsigned short bufj[B * 128];
    const int JC = NPTS / S;

    int gi = blockIdx.x * 128 + threadIdx.x;
    int s  = blockIdx.y;
    int b  = gi >> 13;
    int ib = gi & (NPTS - 1);
    const float* fb = feat + (size_t)b * NPTS * RS;
    int tid = threadIdx.x;

    float xi[D];
    if (PRE) {
        #pragma unroll
        for (int c4 = 0; c4 < D / 4; ++c4) {
            float4 v = *(const float4*)(fb + (size_t)ib * RS + 4 * c4);
            xi[4 * c4] = v.x; xi[4 * c4 + 1] = v.y;
            xi[4 * c4 + 2] = v.z; xi[4 * c4 + 3] = v.w;
        }
    } else {
        #pragma unroll
        for (int c = 0; c < D; ++c) xi[c] = fb[(size_t)ib * RS + c];
    }
    float xxi = 0.f;
    #pragma unroll
    for (int c = 0; c < D; ++c) xxi = fmaf(xi[c], xi[c], xxi);

    float dl[21];
    int   il[21];
    #pragma unroll
    for (int t = 0; t < 21; ++t) { dl[t] = __builtin_inff(); il[t] = 0; }

    float thr = __builtin_inff();          // stale copy of dl[20]
    int   cnt = 0;
    int   j0  = 0;                          // current tile base (absolute)
    const float EPS = 1.52587890625e-05f;   // 2^-16 reassociation cover

    // exact recompute from LDS + strict-< insert (byte-identical to r12);
    // PRE only. Entries are j's from the CURRENT tile (xj live).
    auto insP = [&](int u) {
        if (u < cnt) {
            int j  = (int)bufj[u * 128 + tid];
            int jl = j - j0;
            const float* row = xj + (size_t)jl * D;
            int fsw = jl & 7;
            float dot = 0.f;
            #pragma unroll
            for (int c4 = 0; c4 < D / 4; ++c4) {
                float4 v = *(const float4*)(row + ((c4 ^ fsw) * 4));
                dot = fmaf(xi[4 * c4 + 0], v.x, dot);
                dot = fmaf(xi[4 * c4 + 1], v.y, dot);
                dot = fmaf(xi[4 * c4 + 2], v.z, dot);
                dot = fmaf(xi[4 * c4 + 3], v.w, dot);
            }
            float dd = __builtin_fmaf(-2.f, dot, xxi + xxj[jl]);
            if (dd < dl[20]) {             // strict: ties keep earlier j
                dl[20] = dd; il[20] = j;
                #pragma unroll
                for (int t = 20; t > 0; --t) {
                    if (dl[t] < dl[t - 1]) {
                        float td = dl[t]; dl[t] = dl[t - 1]; dl[t - 1] = td;
                        int   ti = il[t]; il[t] = il[t - 1]; il[t - 1] = ti;
                    }
                }
            }
        }
    };
    auto drainP = [&]() {
        #pragma unroll 1
        for (int u = 0; __any(u < cnt); u += 2) {  // x2: independent chains
            insP(u);
            insP(u + 1);
        }
        cnt = 0;
        thr = dl[20];
    };
    // r12 drain (D=5): buffer carries exact d; entries survive tiles.
    auto drainR12 = [&]() {
        #pragma unroll 1
        for (int u = 0; __any(u < cnt); ++u) {
            if (u < cnt) {
                float dd  = bufd[u * 128 + tid];
                int   jj2 = (int)bufj[u * 128 + tid];
                if (dd < dl[20]) {
                    dl[20] = dd; il[20] = jj2;
                    #pragma unroll
                    for (int t = 20; t > 0; --t) {
                        if (dl[t] < dl[t - 1]) {
                            float td = dl[t]; dl[t] = dl[t - 1]; dl[t - 1] = td;
                            int   ti = il[t]; il[t] = il[t - 1]; il[t - 1] = ti;
                        }
                    }
                }
            }
        }
        cnt = 0;
        thr = dl[20];
    };

    #pragma unroll 1
    for (int t0 = s * JC; t0 < (s + 1) * JC; t0 += TJ) {
        j0 = t0;
        __syncthreads();                   // protect prior-tile xj reads
        // ---- stage xj (+XOR chunk swizzle when PRE) ----
        if (PRE) {
            for (int e = tid; e < TJ * (D / 4); e += 128) {
                int r = e / (D / 4), c4 = e % (D / 4);
                float4 v = *(const float4*)(fb + (size_t)(t0 + r) * RS + 4 * c4);
                *(float4*)(xj + (size_t)r * D + (((c4 ^ (r & 7))) * 4)) = v;
            }
        } else {
            for (int e = tid; e < TJ * D; e += 128) {
                int r = e / D, c = e % D;
                xj[e] = fb[(size_t)(t0 + r) * RS + c];
            }
        }
        // norms from GLOBAL (ascending-c fma chain == knn_merge's recompute)
        if (tid < TJ) {
            const float* row = fb + (size_t)(t0 + tid) * RS;
            float sm = 0.f;
            if (PRE) {
                #pragma unroll
                for (int c4 = 0; c4 < D / 4; ++c4) {
                    float4 v = *(const float4*)(row + 4 * c4);
                    sm = fmaf(v.x, v.x, sm); sm = fmaf(v.y, v.y, sm);
                    sm = fmaf(v.z, v.z, sm); sm = fmaf(v.w, v.w, sm);
                }
            } else {
                #pragma unroll
                for (int c = 0; c < D; ++c) sm = fmaf(row[c], row[c], sm);
            }
            xxj[tid] = sm;
        }
        __syncthreads();

        if (PRE) {
            #pragma unroll 1
            for (int jj = 0; jj < TJ; ++jj) {
                float sum = xxi + xxj[jj];
                const float* xr = xj + (size_t)jj * D;
                int fsw = jj & 7;
                float a0 = 0.f, a1 = 0.f, a2 = 0.f, a3 = 0.f;
                #pragma unroll
                for (int c4 = 0; c4 < D / 4; ++c4) {   // broadcast b128 reads
                    float4 v = *(const float4*)(xr + ((c4 ^ fsw) * 4));
                    a0 = fmaf(xi[4 * c4 + 0], v.x, a0);
                    a1 = fmaf(xi[4 * c4 + 1], v.y, a1);
                    a2 = fmaf(xi[4 * c4 + 2], v.z, a2);
                    a3 = fmaf(xi[4 * c4 + 3], v.w, a3);
                }
                float dot4 = ((a0 + a1) + a2) + a3;
                float da = __builtin_fmaf(-2.f, dot4, sum);
                if (__any(cnt == B)) drainP();
                if (da < __builtin_fmaf(EPS, sum, thr)) {
                    bufj[cnt * 128 + tid] = (unsigned short)(t0 + jj);
                    ++cnt;
                }
            }
            drainP();                      // entries need THIS tile's xj
        } else {
            // ---- r12 path verbatim (exact d buffered, no tile drain) ----
            #pragma unroll 1
            for (int jj = 0; jj < TJ; ++jj) {
                float dot = 0.f;
                #pragma unroll
                for (int c = 0; c < D; ++c) dot = fmaf(xi[c], xj[jj * D + c], dot);
                float d = __builtin_fmaf(-2.f, dot, xxi + xxj[jj]);
                if (__any(cnt == B)) drainR12();
                if (d < thr) {
                    bufd[cnt * 128 + tid] = d;
                    bufj[cnt * 128 + tid] = (unsigned short)(t0 + jj);
                    ++cnt;
                }
            }
        }
    }
    if (!PRE) drainR12();                  // final drain (r12)

    unsigned short* cp =
        (unsigned short*)(xcat + (size_t)gi * 224 + 96) + s * 21;
    #pragma unroll
    for (int t = 0; t < 21; ++t) cp[t] = (unsigned short)il[t];
}

// ===================== KNN phase B: merge S x 21 candidates ================
// Recompute d with the SAME fma ordering as knn_part; insert candidates in
// (split asc, stored rank) order with strict < -> stability == jax top_k.
// Drop entry 0 (self).
template <int D, int RS, int S>
__global__ __launch_bounds__(256) void knn_merge(
    const float* feat, const float* xcat, unsigned short* __restrict__ idxout) {
    int gi = blockIdx.x * 256 + threadIdx.x;
    int b  = gi >> 13;
    int ib = gi & (NPTS - 1);
    const float* fb = feat + (size_t)b * NPTS * RS;

    float xi[D];
    if (D % 4 == 0) {
        #pragma unroll
        for (int c4 = 0; c4 < D / 4; ++c4) {
            float4 v = *(const float4*)(fb + (size_t)ib * RS + 4 * c4);
            xi[4 * c4] = v.x; xi[4 * c4 + 1] = v.y;
            xi[4 * c4 + 2] = v.z; xi[4 * c4 + 3] = v.w;
        }
    } else {
        #pragma unroll
        for (int c = 0; c < D; ++c) xi[c] = fb[(size_t)ib * RS + c];
    }
    float xxi = 0.f;
    #pragma unroll
    for (int c = 0; c < D; ++c) xxi = fmaf(xi[c], xi[c], xxi);

    const unsigned short* cp =
        (const unsigned short*)(xcat + (size_t)gi * 224 + 96);

    float dl[21];
    int   il[21];
    #pragma unroll
    for (int t = 0; t < 21; ++t) { dl[t] = __builtin_inff(); il[t] = 0; }

    for (int t = 0; t < S * 21; ++t) {
        int j = ((int)cp[t]) & (NPTS - 1);
        const float* row = fb + (size_t)j * RS;
        float dot = 0.f, xx = 0.f;
        if (D % 4 == 0) {
            #pragma unroll
            for (int c4 = 0; c4 < D / 4; ++c4) {
                float4 v = *(const float4*)(row + 4 * c4);
                dot = fmaf(xi[4 * c4], v.x, dot);     xx = fmaf(v.x, v.x, xx);
                dot = fmaf(xi[4 * c4 + 1], v.y, dot); xx = fmaf(v.y, v.y, xx);
                dot = fmaf(xi[4 * c4 + 2], v.z, dot); xx = fmaf(v.z, v.z, xx);
                dot = fmaf(xi[4 * c4 + 3], v.w, dot); xx = fmaf(v.w, v.w, xx);
            }
        } else {
            #pragma unroll
            for (int c = 0; c < D; ++c) {
                float v = row[c];
                dot = fmaf(xi[c], v, dot);
                xx  = fmaf(v, v, xx);
            }
        }
        float d = __builtin_fmaf(-2.f, dot, xxi + xx);
        if (d < dl[20]) {
            dl[20] = d; il[20] = j;
            #pragma unroll
            for (int u = 20; u > 0; --u) {
                if (dl[u] < dl[u - 1]) {
                    float td = dl[u]; dl[u] = dl[u - 1]; dl[u - 1] = td;
                    int   ti = il[u]; il[u] = il[u - 1]; il[u - 1] = ti;
                }
            }
        }
    }
    unsigned short* op = idxout + (size_t)gi * KNBR;
    #pragma unroll
    for (int t = 1; t < 21; ++t) op[t - 1] = (unsigned short)il[t];
}

// ===================== EdgeConv (fused BN + leaky + max_k) =================
template <int CIN, int RS, int COUT, int OTILE, int P>
__global__ __launch_bounds__(256) void edgeconv_kernel(
    const float* feat, const unsigned short* __restrict__ knn,
    const float* __restrict__ W, const float* __restrict__ g,
    const float* __restrict__ beta, const float* __restrict__ mu,
    const float* __restrict__ var,
    float* outb, int concat_off) {
    __shared__ float diff[P][KNBR][CIN];
    __shared__ float xil[P][CIN];
    __shared__ unsigned short kidx[P * KNBR];
    __shared__ float sl[OTILE], bl[OTILE], ml[OTILE];

    int tid = threadIdx.x;
    int h   = blockIdx.y;
    int n0  = blockIdx.x * P;                 // P divides 8192 -> same batch
    int b   = n0 >> 13;
    const float* fbase = feat + ((size_t)b << 13) * RS;

    for (int e = tid; e < P * CIN; e += 256)
        xil[e / CIN][e % CIN] = feat[(size_t)(n0 + e / CIN) * RS + e % CIN];
    for (int e = tid; e < P * KNBR; e += 256)
        kidx[e] = knn[(size_t)(n0 + e / KNBR) * KNBR + e % KNBR] & (NPTS - 1);
    for (int e = tid; e < OTILE; e += 256) {
        int o = h * OTILE + e;
        sl[e] = g[o] * rsqrtf(var[o] + 1e-5f);
        bl[e] = beta[o];
        ml[e] = mu[o];
    }
    __syncthreads();

    if (CIN % 4 == 0) {
        for (int e = tid; e < P * KNBR * (CIN / 4); e += 256) {
            int r = e / (CIN / 4), c4 = e % (CIN / 4);
            int p = r / KNBR, k = r % KNBR;
            int j = (int)kidx[r];
            float4 v = *(const float4*)(fbase + (size_t)j * RS + 4 * c4);
            diff[p][k][4 * c4 + 0] = v.x - xil[p][4 * c4 + 0];
            diff[p][k][4 * c4 + 1] = v.y - xil[p][4 * c4 + 1];
            diff[p][k][4 * c4 + 2] = v.z - xil[p][4 * c4 + 2];
            diff[p][k][4 * c4 + 3] = v.w - xil[p][4 * c4 + 3];
        }
    } else {
        for (int e = tid; e < P * KNBR * CIN; e += 256) {
            int r = e / CIN, c = e % CIN;
            int pp = r / KNBR, k = r % KNBR;
            int j = (int)kidx[r];
            diff[pp][k][c] = fbase[(size_t)j * RS + c] - xil[pp][c];
        }
    }
    __syncthreads();

    int ol = tid % OTILE, p = tid / OTILE;
    int o  = h * OTILE + ol;

    float wreg[CIN];
    #pragma unroll
    for (int c = 0; c < CIN; ++c) wreg[c] = W[(size_t)o * (2 * CIN) + c];
    float a = 0.f;
    #pragma unroll
    for (int c = 0; c < CIN; ++c) a = fmaf(wreg[c], xil[p][c], a);
    #pragma unroll
    for (int c = 0; c < CIN; ++c) wreg[c] = W[(size_t)o * (2 * CIN) + CIN + c];

    float s = sl[ol], mm = ml[ol], bb = bl[ol];
    float best = -__builtin_inff();
    for (int k = 0; k < KNBR; ++k) {
        float ac0 = a, ac1 = 0.f, ac2 = 0.f, ac3 = 0.f;
        #pragma unroll
        for (int c = 0; c < CIN; ++c) {
            float d = diff[p][k][c];
            if ((c & 3) == 0)      ac0 = fmaf(wreg[c], d, ac0);
            else if ((c & 3) == 1) ac1 = fmaf(wreg[c], d, ac1);
            else if ((c & 3) == 2) ac2 = fmaf(wreg[c], d, ac2);
            else                   ac3 = fmaf(wreg[c], d, ac3);
        }
        float acc = ((ac0 + ac1) + ac2) + ac3;
        float y = (acc - mm) * s + bb;
        y = (y >= 0.f) ? y : 0.2f * y;
        best = fmaxf(best, y);
    }
    outb[(size_t)(n0 + p) * 224 + concat_off + o] = best;
}

// ===================== conv_global: LDS-tiled GEMM + fused max =============
__global__ __launch_bounds__(256) void convglobal_kernel(
    const float* __restrict__ xcat,
    const float* __restrict__ Wg, const float* __restrict__ gg,
    const float* __restrict__ bg, const float* __restrict__ mg,
    const float* __restrict__ vg,
    float* __restrict__ partial) {
    const int KC = 56, PT = 64, OT = 64, ST = 68;   // ST: padded row stride
    __shared__ float flT[KC * ST];                  // [c][p]  15.2 KB
    __shared__ float WlT[KC * ST];                  // [c][o]  15.2 KB
    __shared__ float red[64 * 17];                  //          4.4 KB

    int tid = threadIdx.x;
    int oi  = tid & 15, pi = tid >> 4;
    int o0  = blockIdx.y * OT;
    int n0  = blockIdx.x * PT;                      // 64 | 8192 -> same batch
    int b   = n0 >> 13;
    int pchunk = blockIdx.x & 127;                  // chunk within batch

    float acc[4][4];
    #pragma unroll
    for (int u = 0; u < 4; ++u)
        #pragma unroll
        for (int v = 0; v < 4; ++v) acc[u][v] = 0.f;

    for (int kc = 0; kc < 224; kc += KC) {
        __syncthreads();
        for (int e = tid; e < PT * (KC / 4); e += 256) {
            int p = e / (KC / 4), c4 = e % (KC / 4);
            float4 v = *(const float4*)(xcat + (size_t)(n0 + p) * 224 + kc + 4 * c4);
            flT[(4 * c4 + 0) * ST + p] = v.x;
            flT[(4 * c4 + 1) * ST + p] = v.y;
            flT[(4 * c4 + 2) * ST + p] = v.z;
            flT[(4 * c4 + 3) * ST + p] = v.w;
        }
        for (int e = tid; e < OT * (KC / 4); e += 256) {
            int o = e / (KC / 4), c4 = e % (KC / 4);
            float4 v = *(const float4*)(Wg + (size_t)(o0 + o) * 224 + kc + 4 * c4);
            WlT[(4 * c4 + 0) * ST + o] = v.x;
            WlT[(4 * c4 + 1) * ST + o] = v.y;
            WlT[(4 * c4 + 2) * ST + o] = v.z;
            WlT[(4 * c4 + 3) * ST + o] = v.w;
        }
        __syncthreads();
        #pragma unroll 8
        for (int c = 0; c < KC; ++c) {
            float4 w4 = *(const float4*)(WlT + c * ST + oi * 4);
            float4 f4 = *(const float4*)(flT + c * ST + pi * 4);
            acc[0][0] = fmaf(w4.x, f4.x, acc[0][0]);
            acc[0][1] = fmaf(w4.x, f4.y, acc[0][1]);
            acc[0][2] = fmaf(w4.x, f4.z, acc[0][2]);
            acc[0][3] = fmaf(w4.x, f4.w, acc[0][3]);
            acc[1][0] = fmaf(w4.y, f4.x, acc[1][0]);
            acc[1][1] = fmaf(w4.y, f4.y, acc[1][1]);
            acc[1][2] = fmaf(w4.y, f4.z, acc[1][2]);
            acc[1][3] = fmaf(w4.y, f4.w, acc[1][3]);
            acc[2][0] = fmaf(w4.z, f4.x, acc[2][0]);
            acc[2][1] = fmaf(w4.z, f4.y, acc[2][1]);
            acc[2][2] = fmaf(w4.z, f4.z, acc[2][2]);
            acc[2][3] = fmaf(w4.z, f4.w, acc[2][3]);
            acc[3][0] = fmaf(w4.w, f4.x, acc[3][0]);
            acc[3][1] = fmaf(w4.w, f4.y, acc[3][1]);
            acc[3][2] = fmaf(w4.w, f4.z, acc[3][2]);
            acc[3][3] = fmaf(w4.w, f4.w, acc[3][3]);
        }
    }
    #pragma unroll
    for (int u = 0; u < 4; ++u) {
        int oL = oi * 4 + u, o = o0 + oL;
        float s = gg[o] * rsqrtf(vg[o] + 1e-5f);
        float mm = mg[o], bb = bg[o];
        float best = -__builtin_inff();
        #pragma unroll
        for (int v = 0; v < 4; ++v) {
            float y = (acc[u][v] - mm) * s + bb;
            y = (y >= 0.f) ? y : 0.2f * y;
            best = fmaxf(best, y);
        }
        red[oL * 17 + pi] = best;
    }
    __syncthreads();
    if (tid < 64) {
        float best = -__builtin_inff();
        #pragma unroll
        for (int q = 0; q < 16; ++q) best = fmaxf(best, red[tid * 17 + q]);
        partial[((size_t)(b * 128 + pchunk)) * 256 + o0 + tid] = best;
    }
}

__global__ void reduce_gfeat_kernel(const float* __restrict__ partial,
                                    float* __restrict__ gfeat,
                                    float* __restrict__ outg) {
    int b = blockIdx.x, o = threadIdx.x;
    float best = -__builtin_inff();
    for (int ch = 0; ch < 128; ++ch)
        best = fmaxf(best, partial[((size_t)b * 128 + ch) * 256 + o]);
    gfeat[b * 256 + o] = best;
    outg[b * 256 + o]  = best;
}

// ===================== heads (per-batch block) =============================
__global__ __launch_bounds__(256) void heads_kernel(
    const float* __restrict__ gfeat,
    const float* __restrict__ Wv1, const float* __restrict__ bv1,
    const float* __restrict__ Wv2, const float* __restrict__ bv2,
    const float* __restrict__ Wq1, const float* __restrict__ bq1,
    const float* __restrict__ Wq2, const float* __restrict__ bq2,
    float* __restrict__ out) {
    int b = blockIdx.x, t = threadIdx.x;
    __shared__ float gf[256], h[512], q[64];
    gf[t] = gfeat[b * 256 + t];
    __syncthreads();
    for (int r = t; r < 512; r += 256) {
        float acc = bv1[r];
        for (int c = 0; c < 256; ++c) acc = fmaf(Wv1[r * 256 + c], gf[c], acc);
        h[r] = fmaxf(acc, 0.f);
    }
    __syncthreads();
    if (t < 192) {
        float acc = bv2[t];
        for (int c = 0; c < 512; ++c) acc = fmaf(Wv2[t * 512 + c], h[c], acc);
        out[b * 192 + t] = acc;               // vertex_coords
    } else {
        int r = t - 192;
        if (r < 64) {
            float acc = bq1[r];
            for (int c = 0; c < 256; ++c) acc = fmaf(Wq1[r * 256 + c], gf[c], acc);
            q[r] = fmaxf(acc, 0.f);
        }
    }
    __syncthreads();
    if (t == 0) {
        float acc = bq2[0];
        for (int c = 0; c < 64; ++c) acc = fmaf(Wq2[c], q[c], acc);
        float nv = 1.0f / (1.0f + expf(-acc));
        out[772 + b] = nv;                                       // nvs
        float num = fminf(fmaxf(rintf(nv * 64.0f), 1.0f), 64.0f);
        out[768 + b] = num;                                      // num_vertices
    }
}

// ============================== launch =====================================
extern "C" void kernel_launch(void* const* d_in, const int* in_sizes, int n_in,
                              void* d_out, int out_size, void* d_ws, size_t ws_size,
                              hipStream_t stream) {
    (void)in_sizes; (void)n_in; (void)out_size; (void)ws_size;
    const float* x   = (const float*)d_in[0];
    const float* W1  = (const float*)d_in[1];
    const float* g1  = (const float*)d_in[2];
    const float* b1  = (const float*)d_in[3];
    const float* m1  = (const float*)d_in[4];
    const float* v1  = (const float*)d_in[5];
    const float* W2  = (const float*)d_in[6];
    const float* g2  = (const float*)d_in[7];
    const float* b2  = (const float*)d_in[8];
    const float* m2  = (const float*)d_in[9];
    const float* v2  = (const float*)d_in[10];
    const float* W3  = (const float*)d_in[11];
    const float* g3  = (const float*)d_in[12];
    const float* b3  = (const float*)d_in[13];
    const float* m3  = (const float*)d_in[14];
    const float* v3  = (const float*)d_in[15];
    const float* Wg  = (const float*)d_in[16];
    const float* gg  = (const float*)d_in[17];
    const float* bg  = (const float*)d_in[18];
    const float* mg  = (const float*)d_in[19];
    const float* vg  = (const float*)d_in[20];
    const float* Wv1 = (const float*)d_in[21];
    const float* bv1 = (const float*)d_in[22];
    const float* Wv2 = (const float*)d_in[23];
    const float* bv2 = (const float*)d_in[24];
    const float* Wq1 = (const float*)d_in[25];
    const float* bq1 = (const float*)d_in[26];
    const float* Wq2 = (const float*)d_in[27];
    const float* bq2 = (const float*)d_in[28];

    float* out  = (float*)d_out;
    float* xcat = out + 1800;                    // f32 [4,8192,224]
    char* ws = (char*)d_ws;
    const int ROWS = BATCH * NPTS;   // 32768

    // ws layout (1,310,720 B; part/gft alias idx AFTER it is dead):
    unsigned short* idx  = (unsigned short*)(ws);        // [32768,20] u16
    float*          part = (float*)(ws);                 // [512,256] f32 (alias)
    float*          gft  = (float*)(ws + 524288);        // [4,256]   f32 (alias)

    // ---- EdgeConv 1: 5 -> 32
    knn_part<5, 5, 8, 128, 8><<<dim3(ROWS / 128, 8), 128, 0, stream>>>(x, xcat);
    knn_merge<5, 5, 8><<<ROWS / 256, 256, 0, stream>>>(x, xcat, idx);
    edgeconv_kernel<5, 5, 32, 32, 8>
        <<<dim3(ROWS / 8, 1), 256, 0, stream>>>(x, idx, W1, g1, b1, m1, v1, xcat, 0);

    // ---- EdgeConv 2: 32 -> 64 (features from xcat[:,0:32))
    knn_part<32, 224, 8, 128, 16><<<dim3(ROWS / 128, 8), 128, 0, stream>>>(xcat, xcat);
    knn_merge<32, 224, 8><<<ROWS / 256, 256, 0, stream>>>(xcat, xcat, idx);
    edgeconv_kernel<32, 224, 64, 64, 4>
        <<<dim3(ROWS / 4, 1), 256, 0, stream>>>(xcat, idx, W2, g2, b2, m2, v2, xcat, 32);

    // ---- EdgeConv 3: 64 -> 128 (features from xcat[:,32:96))
    knn_part<64, 224, 8, 64, 16><<<dim3(ROWS / 128, 8), 128, 0, stream>>>(xcat + 32, xcat);
    knn_merge<64, 224, 8><<<ROWS / 256, 256, 0, stream>>>(xcat + 32, xcat, idx);
    edgeconv_kernel<64, 224, 128, 64, 4>
        <<<dim3(ROWS / 4, 2), 256, 0, stream>>>(xcat + 32, idx, W3, g3, b3, m3, v3, xcat, 96);

    // ---- conv_global (224->256) + max over N  (idx dead; part aliases it)
    convglobal_kernel<<<dim3(ROWS / 64, 4), 256, 0, stream>>>(
        xcat, Wg, gg, bg, mg, vg, part);
    reduce_gfeat_kernel<<<BATCH, 256, 0, stream>>>(part, gft, out + 776);

    // ---- heads
    heads_kernel<<<BATCH, 256, 0, stream>>>(
        gft, Wv1, bv1, Wv2, bv2, Wq1, bq1, Wq2, bq2, out);
}